// Round 3
// baseline (2401.837 us; speedup 1.0000x reference)
//
#include <hip/hip_runtime.h>
#include <cstdint>
#include <cmath>

#define S_LEN 1024
#define BATCH 64
#define IN_SZ 256
#define HID 512
#define OUT_SZ 256
#define WIH_LD 768  // W_ih leading dim = IN_SZ + HID
#define BH (BATCH * HID)            // 32768
#define XP_FLOATS (S_LEN * BH)      // 33,554,432 floats (128 MB)

// Weight pair-index space: p = k/2, p in [0,256). Per output row j (0..511):
//   p in [0,176)    -> VGPR/AGPR-resident (wregbuf[p*512 + j])        [verified sweet spot]
//   p in [176,252)  -> LDS-resident, TRANSPOSED per-j rows, b128 reads
//   p in [252,256)  -> register-resident uint4, loaded ONCE (step-invariant)
//
// R3 hypothesis: R2's wall (~3682 cyc/step) was the per-step L2 re-fetch of
// the 56 streamed pairs (114 KB/step/CU at ~31-56 B/cyc L1<->L2 link = 2000+
// cyc). This round eliminates ALL per-step weight streaming: 76 pairs move to
// LDS (transposed rows -> 19 ds_read_b128/thread vs 24 b32 before; net LDS
// insts 89->84), last 4 pairs live in 4 registers for the whole kernel.
//
// LDS weight layout: row j = 76 consecutive pair-words, stride 76 words.
// Raw banking: lanes j === j' (mod 8) collide 8-way (12*8=96===0 mod 32).
// Fix: XOR word-address bits [4:2] with t=(j>>3)&7. Within a collision set
// (j&7 fixed, t=0..7) pre-XOR cluster is identical (152t===0 mod 8), so ^t
// spreads the 8 lanes over all 8 bank clusters -> conflict-free b128.
// pack_w pre-applies the swizzle in global memory; rnn stages linearly.
#define P_REG 176
#define P_LDS 76     // 76*512 words = 155,648 B LDS (+2 KB h2u = 157,696 <= 160 KiB)

// ws word layout after xp (wbase = ws + XP_FLOATS):
//  [0, 2048)           wstr      (512 uint4; rnn loads once; dead after rnn)
//  [2048, 92160)       wregbuf   (176*512; dead after rnn)
//  [92160, 131072)     wldsbuf   (76*512 swizzled LDS image; dead after rnn)
//  [131072, 196608)    wpk       (xproj B-fragments, 16384 uint4 = 256 KB)
//  overlays (used only after rnn completes):
//  [0, 65536)          sc_g[64][1024]
//  [65536, 98304)      ctx_g[64][512]

typedef _Float16 h2v __attribute__((ext_vector_type(2)));
typedef _Float16 f16x8 __attribute__((ext_vector_type(8)));
typedef float f32x4 __attribute__((ext_vector_type(4)));

__device__ __forceinline__ float dot2p(unsigned int a, unsigned int b, float c) {
#if __has_builtin(__builtin_amdgcn_fdot2)
    return __builtin_amdgcn_fdot2(__builtin_bit_cast(h2v, a),
                                  __builtin_bit_cast(h2v, b), c, false);
#else
    h2v av = __builtin_bit_cast(h2v, a);
    h2v bv = __builtin_bit_cast(h2v, b);
    return c + (float)av.x * (float)bv.x + (float)av.y * (float)bv.y;
#endif
}

// Branch-free tanh: 1 - 2/(e^{2x}+1). ~1e-6 abs err, exact limits. (R2 win.)
__device__ __forceinline__ float fast_tanh(float x) {
    float e = __expf(2.0f * x);
#if __has_builtin(__builtin_amdgcn_rcpf)
    float r = __builtin_amdgcn_rcpf(e + 1.0f);
#else
    float r = 1.0f / (e + 1.0f);
#endif
    return __builtin_fmaf(-2.0f, r, 1.0f);
}

__global__ __launch_bounds__(256) void pack_w(const float* __restrict__ W_ih,
                                              unsigned int* __restrict__ wstr,
                                              unsigned int* __restrict__ wregbuf,
                                              unsigned int* __restrict__ wldsbuf) {
    int idx = blockIdx.x * 256 + threadIdx.x;   // 0..131071
    int p = idx & 255;
    int j = idx >> 8;
    const float* src = W_ih + (size_t)j * WIH_LD + IN_SZ + 2 * p;
    unsigned short lo = __builtin_bit_cast(unsigned short, (_Float16)src[0]);
    unsigned short hi = __builtin_bit_cast(unsigned short, (_Float16)src[1]);
    unsigned int u = (unsigned int)lo | ((unsigned int)hi << 16);
    if (p < P_REG) {
        wregbuf[p * 512 + j] = u;
    } else if (p < P_REG + P_LDS) {
        // Transposed row-major per j, XOR-swizzled word address (see header).
        int w = (j * P_LDS + (p - P_REG)) ^ (((j >> 3) & 7) << 2);
        wldsbuf[w] = u;
    } else {
        int q = p - (P_REG + P_LDS);   // 0..3
        wstr[j * 4 + q] = u;           // one uint4 per j, loaded once by rnn
    }
}

// Pack Wx (W_ih[:, 0:256]) into MFMA B-fragment layout, f16.
__global__ __launch_bounds__(256) void pack_wf16(const float* __restrict__ W_ih,
                                                 uint4* __restrict__ wpk) {
    int idx = blockIdx.x * 256 + threadIdx.x;   // 0..16383
    if (idx >= 16384) return;
    int nt   = idx >> 9;
    int ks   = (idx >> 6) & 7;
    int lane = idx & 63;
    int n  = nt * 16 + (lane & 15);
    int kb = ks * 32 + (lane >> 4) * 8;
    const float* src = W_ih + (size_t)n * WIH_LD + kb;
    union { uint4 u; _Float16 h[8]; } v;
#pragma unroll
    for (int i = 0; i < 8; ++i) v.h[i] = (_Float16)src[i];
    wpk[idx] = v.u;
}

// xp[s][b][h] = dot(x[b][s][:], Wx[h][:]) + b_ih[h], via f16 MFMA (fp32 accum).
#define AH_LD 264   // 256 + 8-half pad
__global__ __launch_bounds__(256) void xproj_mfma(const float* __restrict__ x,
                                                  const uint4* __restrict__ wpk,
                                                  const float* __restrict__ b_ih,
                                                  float* __restrict__ xp) {
    const int s    = blockIdx.x;
    const int half = blockIdx.y;
    const int tid  = threadIdx.x;
    __shared__ __align__(16) _Float16 Ah[32 * AH_LD];
    __shared__ float bsh[HID];
    bsh[tid] = b_ih[tid];
    bsh[tid + 256] = b_ih[tid + 256];
    {
        int r  = tid >> 3;
        int c0 = (tid & 7) * 32;
        const float4* s4 = (const float4*)(x + ((size_t)(half * 32 + r) * S_LEN + s) * IN_SZ + c0);
        _Float16* dst = &Ah[r * AH_LD + c0];
#pragma unroll
        for (int i = 0; i < 8; ++i) {
            float4 v = s4[i];
            dst[4 * i + 0] = (_Float16)v.x;
            dst[4 * i + 1] = (_Float16)v.y;
            dst[4 * i + 2] = (_Float16)v.z;
            dst[4 * i + 3] = (_Float16)v.w;
        }
    }
    __syncthreads();
    const int lane = tid & 63;
    const int w    = tid >> 6;
    const int mt   = w & 1;
    const int ntb  = (w >> 1) * 16;
    f16x8 areg[8];
#pragma unroll
    for (int ks = 0; ks < 8; ++ks)
        areg[ks] = *(const f16x8*)&Ah[(mt * 16 + (lane & 15)) * AH_LD + ks * 32 + (lane >> 4) * 8];
    const int brow  = half * 32 + mt * 16 + (lane >> 4) * 4;
    const int ncol0 = lane & 15;
    for (int nt2 = 0; nt2 < 16; ++nt2) {
        int nt = ntb + nt2;
        const uint4* bp = wpk + (size_t)nt * 8 * 64 + lane;
        f32x4 acc = {0.f, 0.f, 0.f, 0.f};
#pragma unroll
        for (int ks = 0; ks < 8; ++ks) {
            uint4 bu = bp[ks * 64];
            acc = __builtin_amdgcn_mfma_f32_16x16x32_f16(
                areg[ks], __builtin_bit_cast(f16x8, bu), acc, 0, 0, 0);
        }
        int n = nt * 16 + ncol0;
        float bias = bsh[n];
        float* outp = xp + (size_t)s * BH + (size_t)brow * HID + n;
#pragma unroll
        for (int r = 0; r < 4; ++r) outp[(size_t)r * HID] = acc[r] + bias;
    }
}

// Recurrence: one WG (512 thr, 8 waves, 2/SIMD) per batch.
// R3: zero per-step weight streaming (all weights reg/LDS-resident);
// xpv software-pipelined one step ahead.
__global__ __launch_bounds__(512, 2) void rnn_f16(const unsigned int* __restrict__ wregbuf,
                                                  const unsigned int* __restrict__ wldsbuf,
                                                  const uint4* __restrict__ wstr,
                                                  float* __restrict__ xp) {
    const int b = blockIdx.x;
    const int j = threadIdx.x;

    __shared__ __align__(16) unsigned int wlds[P_LDS * 512];   // 155,648 B, swizzled image
    __shared__ __align__(16) unsigned short h2u[2][512];       // 2 KB, packed f16 state

    unsigned int wreg[P_REG];
#pragma unroll
    for (int p = 0; p < P_REG; ++p) wreg[p] = wregbuf[p * 512 + j];
    const uint4 sw = wstr[j];    // pairs 252..255, step-invariant, stays in 4 VGPRs

    // Linear copy of the pre-swizzled LDS image (coalesced global, linear LDS).
    for (int w = j; w < P_LDS * 512; w += 512) wlds[w] = wldsbuf[w];
    h2u[0][j] = 0;   // f16 +0.0
    __syncthreads();

    const unsigned int swz   = ((j >> 3) & 7) << 2;   // word-index XOR (bits [4:2])
    const unsigned int wbase = (unsigned int)j * P_LDS;

    float* col = xp + (size_t)b * HID + j;
    float xpv = col[0];
    for (int s = 0; s < S_LEN; ++s) {
        const unsigned int* hq = (const unsigned int*)h2u[s & 1];  // 256 pairs
        // Prefetch next step's xp (consumed next iteration; full step to land).
        // s=1023 over-reads into the dead weight-table region of ws: harmless.
        float xpn = col[(size_t)(s + 1) * BH];

        float a0 = 0.f, a1 = 0.f, a2 = 0.f, a3 = 0.f;
#pragma unroll
        for (int p = 0; p < P_REG; p += 4) {
            a0 = dot2p(wreg[p + 0], hq[p + 0], a0);
            a1 = dot2p(wreg[p + 1], hq[p + 1], a1);
            a2 = dot2p(wreg[p + 2], hq[p + 2], a2);
            a3 = dot2p(wreg[p + 3], hq[p + 3], a3);
        }
#pragma unroll
        for (int kk = 0; kk < P_LDS / 4; ++kk) {        // 19 x ds_read_b128
            unsigned int w = (wbase + 4 * kk) ^ swz;    // 16B-aligned (w % 4 == 0)
            uint4 wv = *(const uint4*)&wlds[w];
            int pb = P_REG + 4 * kk;
            a0 = dot2p(wv.x, hq[pb + 0], a0);
            a1 = dot2p(wv.y, hq[pb + 1], a1);
            a2 = dot2p(wv.z, hq[pb + 2], a2);
            a3 = dot2p(wv.w, hq[pb + 3], a3);
        }
        {   // register-resident tail, pairs 252..255
            int pb = P_REG + P_LDS;
            a0 = dot2p(sw.x, hq[pb + 0], a0);
            a1 = dot2p(sw.y, hq[pb + 1], a1);
            a2 = dot2p(sw.z, hq[pb + 2], a2);
            a3 = dot2p(sw.w, hq[pb + 3], a3);
        }

        float v = fast_tanh(((a0 + a1) + (a2 + a3)) + xpv);
        col[(size_t)s * BH] = v;                                   // hidden_seq (fp32)
        h2u[(s + 1) & 1][j] = __builtin_bit_cast(unsigned short, (_Float16)v);
        // Relaxed barrier: wait LDS only; global store/loads stay in flight.
        asm volatile("s_waitcnt lgkmcnt(0)" ::: "memory");
        asm volatile("s_barrier" ::: "memory");
        xpv = xpn;
    }
}

// scores: sc_g[b][s] = dot(hbuf[s][b][:], hbuf[S-1][b][:]). Grid (64, 8), 256 thr.
__global__ __launch_bounds__(256) void attn_sc(const float* __restrict__ hbuf,
                                               float* __restrict__ sc_g) {
    const int b     = blockIdx.x;
    const int chunk = blockIdx.y;
    const int tid   = threadIdx.x;
    const int lane  = tid & 63;
    const int wv    = tid >> 6;
    __shared__ float fh[HID];
    fh[tid] = hbuf[(size_t)(S_LEN - 1) * BH + (size_t)b * HID + tid];
    fh[tid + 256] = hbuf[(size_t)(S_LEN - 1) * BH + (size_t)b * HID + tid + 256];
    __syncthreads();
    float4 f0 = *(const float4*)&fh[lane * 8];
    float4 f1 = *(const float4*)&fh[lane * 8 + 4];
    for (int i = 0; i < 32; ++i) {
        int s = chunk * 128 + wv * 32 + i;
        const float* hr = hbuf + (size_t)s * BH + (size_t)b * HID + lane * 8;
        float4 a0 = *(const float4*)hr;
        float4 a1 = *(const float4*)(hr + 4);
        float p = a0.x * f0.x + a0.y * f0.y + a0.z * f0.z + a0.w * f0.w +
                  a1.x * f1.x + a1.y * f1.y + a1.z * f1.z + a1.w * f1.w;
#pragma unroll
        for (int off = 32; off; off >>= 1) p += __shfl_down(p, off, 64);
        if (lane == 0) sc_g[(size_t)b * S_LEN + s] = p;
    }
}

// softmax (redundant per h-chunk) + context. Grid (64, 4), 256 thr, 128 h/WG.
__global__ __launch_bounds__(256) void attn_ctx(const float* __restrict__ hbuf,
                                                const float* __restrict__ sc_g,
                                                float* __restrict__ ctx_g) {
    const int b   = blockIdx.x;
    const int hc  = blockIdx.y * 128;
    const int tid = threadIdx.x;
    const int lane = tid & 63;
    const int wv   = tid >> 6;
    __shared__ float sc[S_LEN];
    __shared__ float red[4];
    __shared__ float part[256];
    for (int i = tid; i < S_LEN; i += 256) sc[i] = sc_g[(size_t)b * S_LEN + i];
    __syncthreads();
    float m = -1e30f;
    for (int i = tid; i < S_LEN; i += 256) m = fmaxf(m, sc[i]);
#pragma unroll
    for (int off = 32; off; off >>= 1) m = fmaxf(m, __shfl_down(m, off, 64));
    if (lane == 0) red[wv] = m;
    __syncthreads();
    m = fmaxf(fmaxf(red[0], red[1]), fmaxf(red[2], red[3]));
    float sum = 0.f;
    for (int i = tid; i < S_LEN; i += 256) {
        float e = __expf(sc[i] - m);
        sc[i] = e;
        sum += e;
    }
#pragma unroll
    for (int off = 32; off; off >>= 1) sum += __shfl_down(sum, off, 64);
    __syncthreads();
    if (lane == 0) red[wv] = sum;
    __syncthreads();
    float inv = 1.f / (red[0] + red[1] + red[2] + red[3]);
    const int h  = hc + (tid & 127);
    const int sh = tid >> 7;
    const float* hp = hbuf + (size_t)sh * 512 * BH + (size_t)b * HID + h;
    float c = 0.f;
#pragma unroll 4
    for (int s2 = 0; s2 < 512; ++s2)
        c += sc[sh * 512 + s2] * hp[(size_t)s2 * BH];
    part[tid] = c;
    __syncthreads();
    if (tid < 128) ctx_g[(size_t)b * HID + hc + tid] = (part[tid] + part[tid + 128]) * inv;
}

// out[b][o] = b_ho[o] + dot(ctx_g[b][:], W_ho[o][:]). Grid 64, 256 thr.
__global__ __launch_bounds__(256) void attn_fin(const float* __restrict__ ctx_g,
                                                const float* __restrict__ W_ho,
                                                const float* __restrict__ b_ho,
                                                float* __restrict__ out) {
    const int b   = blockIdx.x;
    const int tid = threadIdx.x;
    __shared__ float ctx[HID];
    ctx[tid] = ctx_g[(size_t)b * HID + tid];
    ctx[tid + 256] = ctx_g[(size_t)b * HID + tid + 256];
    __syncthreads();
    float o = b_ho[tid];
    const float* wr = W_ho + (size_t)tid * HID;
#pragma unroll 4
    for (int k = 0; k < HID; ++k) o += wr[k] * ctx[k];
    out[(size_t)b * OUT_SZ + tid] = o;
}

extern "C" void kernel_launch(void* const* d_in, const int* in_sizes, int n_in,
                              void* d_out, int out_size, void* d_ws, size_t ws_size,
                              hipStream_t stream) {
    const float* x    = (const float*)d_in[0];
    const float* W_ih = (const float*)d_in[1];
    const float* b_ih = (const float*)d_in[2];
    const float* W_ho = (const float*)d_in[3];
    const float* b_ho = (const float*)d_in[4];
    float* out = (float*)d_out;
    float* ws  = (float*)d_ws;

    float* xp = ws;
    unsigned int* wbase   = (unsigned int*)(ws + XP_FLOATS);
    unsigned int* wstr    = wbase;                         // 2048 words (512 uint4)
    unsigned int* wregbuf = wbase + 2048;                  // 90112 words
    unsigned int* wldsbuf = wbase + 2048 + P_REG * 512;    // 38912 words -> ends at 131072
    uint4*        wpk     = (uint4*)(wbase + 131072);      // 16384 uint4 (256 KB)
    float*        sc_g    = (float*)wbase;                 // overlay, post-rnn
    float*        ctx_g   = (float*)(wbase + 65536);       // overlay, post-rnn

    pack_w<<<dim3(512), dim3(256), 0, stream>>>(W_ih, wstr, wregbuf, wldsbuf);
    pack_wf16<<<dim3(64), dim3(256), 0, stream>>>(W_ih, wpk);
    xproj_mfma<<<dim3(1024, 2), dim3(256), 0, stream>>>(x, wpk, b_ih, xp);
    rnn_f16<<<dim3(64), dim3(512), 0, stream>>>(wregbuf, wldsbuf, (const uint4*)wstr, xp);
    attn_sc<<<dim3(64, 8), dim3(256), 0, stream>>>(xp, sc_g);
    attn_ctx<<<dim3(64, 4), dim3(256), 0, stream>>>(xp, sc_g, ctx_g);
    attn_fin<<<dim3(64), dim3(256), 0, stream>>>(ctx_g, W_ho, b_ho, out);
}

// Round 4
// 1730.655 us; speedup vs baseline: 1.3878x; 1.3878x over previous
//
#include <hip/hip_runtime.h>
#include <cstdint>
#include <cmath>

#define S_LEN 1024
#define BATCH 64
#define IN_SZ 256
#define HID 512
#define OUT_SZ 256
#define WIH_LD 768  // W_ih leading dim = IN_SZ + HID
#define BH (BATCH * HID)            // 32768
#define XP_FLOATS (S_LEN * BH)      // 33,554,432 floats (128 MB)

// Weight pair-index space: p = k/2, p in [0,256). Per output row j (0..511):
//   p in [0,176)    -> VGPR/AGPR-resident (wregbuf[p*512 + j])   [verified sweet spot]
//   p in [176,200)  -> LDS-resident, [p2][j][2] layout, ds_read_b64
//   p in [200,256)  -> streamed/step from L2 (wstr uint4, single upfront batch)
//
// R4 model (from R2/R3 counters): the LDS pipe is the serial resource:
//   512 uniform hq b128 (~5cyc) + weight reads + writes ~= 3682 cyc/step.
// Weights-in-registers are FREE (dot2 operand reads). LDS weight *bytes* are
// expensive (128 B/clk data path) -> keep LDS weight volume at 24 pairs but
// halve the ISSUE count: [p2][j][2] pairs adjacent per j -> 12 x b64/thread.
// Banking: lane j reads words {2j, 2j+1}: the canonical stride-2 float2
// pattern, conflict-free (lanes 16 apart land in different 16-lane phases).
// R3's transposed b128 + XOR swizzle is ABANDONED: it tripled LDS weight
// bytes AND had cross-set bank collisions (5e7 conflicts measured).
#define P_REG 176
#define P_LDS 24
#define P_LDS2 (P_LDS / 2)   // 12 b64 groups
#define P_STR_G 14   // 14 groups x 4 pairs = 56 pairs

// ws word layout after xp (wbase = ws + XP_FLOATS):
//  [0, 28672)          wstr      (rnn; dead after rnn)
//  [28672, 118784)     wregbuf   (rnn; dead after rnn)
//  [118784, 131072)    wldsbuf   (12*1024 words, [p2][j][2]; dead after rnn)
//  [131072, 196608)    wpk       (xproj B-fragments, 16384 uint4 = 256 KB)
//  overlays (used only after rnn completes):
//  [0, 65536)          sc_g[64][1024]
//  [65536, 98304)      ctx_g[64][512]

typedef _Float16 h2v __attribute__((ext_vector_type(2)));
typedef _Float16 f16x8 __attribute__((ext_vector_type(8)));
typedef float f32x4 __attribute__((ext_vector_type(4)));

__device__ __forceinline__ float dot2p(unsigned int a, unsigned int b, float c) {
#if __has_builtin(__builtin_amdgcn_fdot2)
    return __builtin_amdgcn_fdot2(__builtin_bit_cast(h2v, a),
                                  __builtin_bit_cast(h2v, b), c, false);
#else
    h2v av = __builtin_bit_cast(h2v, a);
    h2v bv = __builtin_bit_cast(h2v, b);
    return c + (float)av.x * (float)bv.x + (float)av.y * (float)bv.y;
#endif
}

// Branch-free tanh: 1 - 2/(e^{2x}+1). ~1e-6 abs err, exact limits. (R2 win.)
__device__ __forceinline__ float fast_tanh(float x) {
    float e = __expf(2.0f * x);
#if __has_builtin(__builtin_amdgcn_rcpf)
    float r = __builtin_amdgcn_rcpf(e + 1.0f);
#else
    float r = 1.0f / (e + 1.0f);
#endif
    return __builtin_fmaf(-2.0f, r, 1.0f);
}

__global__ __launch_bounds__(256) void pack_w(const float* __restrict__ W_ih,
                                              unsigned int* __restrict__ wstr,
                                              unsigned int* __restrict__ wregbuf,
                                              unsigned int* __restrict__ wldsbuf) {
    int idx = blockIdx.x * 256 + threadIdx.x;   // 0..131071
    int p = idx & 255;
    int j = idx >> 8;
    const float* src = W_ih + (size_t)j * WIH_LD + IN_SZ + 2 * p;
    unsigned short lo = __builtin_bit_cast(unsigned short, (_Float16)src[0]);
    unsigned short hi = __builtin_bit_cast(unsigned short, (_Float16)src[1]);
    unsigned int u = (unsigned int)lo | ((unsigned int)hi << 16);
    if (p < P_REG) {
        wregbuf[p * 512 + j] = u;
    } else if (p < P_REG + P_LDS) {
        int d  = p - P_REG;
        int p2 = d >> 1;
        int q  = d & 1;
        wldsbuf[p2 * 1024 + j * 2 + q] = u;   // [p2][j][2] -> b64 per thread
    } else {
        int q = p - (P_REG + P_LDS);
        wstr[((q >> 2) * 512 + j) * 4 + (q & 3)] = u;
    }
}

// Pack Wx (W_ih[:, 0:256]) into MFMA B-fragment layout, f16.
__global__ __launch_bounds__(256) void pack_wf16(const float* __restrict__ W_ih,
                                                 uint4* __restrict__ wpk) {
    int idx = blockIdx.x * 256 + threadIdx.x;   // 0..16383
    if (idx >= 16384) return;
    int nt   = idx >> 9;
    int ks   = (idx >> 6) & 7;
    int lane = idx & 63;
    int n  = nt * 16 + (lane & 15);
    int kb = ks * 32 + (lane >> 4) * 8;
    const float* src = W_ih + (size_t)n * WIH_LD + kb;
    union { uint4 u; _Float16 h[8]; } v;
#pragma unroll
    for (int i = 0; i < 8; ++i) v.h[i] = (_Float16)src[i];
    wpk[idx] = v.u;
}

// xp[s][b][h] = dot(x[b][s][:], Wx[h][:]) + b_ih[h], via f16 MFMA (fp32 accum).
#define AH_LD 264   // 256 + 8-half pad
__global__ __launch_bounds__(256) void xproj_mfma(const float* __restrict__ x,
                                                  const uint4* __restrict__ wpk,
                                                  const float* __restrict__ b_ih,
                                                  float* __restrict__ xp) {
    const int s    = blockIdx.x;
    const int half = blockIdx.y;
    const int tid  = threadIdx.x;
    __shared__ __align__(16) _Float16 Ah[32 * AH_LD];
    __shared__ float bsh[HID];
    bsh[tid] = b_ih[tid];
    bsh[tid + 256] = b_ih[tid + 256];
    {
        int r  = tid >> 3;
        int c0 = (tid & 7) * 32;
        const float4* s4 = (const float4*)(x + ((size_t)(half * 32 + r) * S_LEN + s) * IN_SZ + c0);
        _Float16* dst = &Ah[r * AH_LD + c0];
#pragma unroll
        for (int i = 0; i < 8; ++i) {
            float4 v = s4[i];
            dst[4 * i + 0] = (_Float16)v.x;
            dst[4 * i + 1] = (_Float16)v.y;
            dst[4 * i + 2] = (_Float16)v.z;
            dst[4 * i + 3] = (_Float16)v.w;
        }
    }
    __syncthreads();
    const int lane = tid & 63;
    const int w    = tid >> 6;
    const int mt   = w & 1;
    const int ntb  = (w >> 1) * 16;
    f16x8 areg[8];
#pragma unroll
    for (int ks = 0; ks < 8; ++ks)
        areg[ks] = *(const f16x8*)&Ah[(mt * 16 + (lane & 15)) * AH_LD + ks * 32 + (lane >> 4) * 8];
    const int brow  = half * 32 + mt * 16 + (lane >> 4) * 4;
    const int ncol0 = lane & 15;
    for (int nt2 = 0; nt2 < 16; ++nt2) {
        int nt = ntb + nt2;
        const uint4* bp = wpk + (size_t)nt * 8 * 64 + lane;
        f32x4 acc = {0.f, 0.f, 0.f, 0.f};
#pragma unroll
        for (int ks = 0; ks < 8; ++ks) {
            uint4 bu = bp[ks * 64];
            acc = __builtin_amdgcn_mfma_f32_16x16x32_f16(
                areg[ks], __builtin_bit_cast(f16x8, bu), acc, 0, 0, 0);
        }
        int n = nt * 16 + ncol0;
        float bias = bsh[n];
        float* outp = xp + (size_t)s * BH + (size_t)brow * HID + n;
#pragma unroll
        for (int r = 0; r < 4; ++r) outp[(size_t)r * HID] = acc[r] + bias;
    }
}

// Recurrence: one WG (512 thr, 8 waves, 2/SIMD) per batch. R2 structure
// (verified 1571 us) with ONE change: LDS weights read as 12 x b64 instead
// of 24 x b32 ([p2][j][2] layout, stride-2 conflict-free banking).
__global__ __launch_bounds__(512, 2) void rnn_f16(const unsigned int* __restrict__ wregbuf,
                                                  const unsigned int* __restrict__ wldsbuf,
                                                  const uint4* __restrict__ wstr,
                                                  float* __restrict__ xp) {
    const int b = blockIdx.x;
    const int j = threadIdx.x;

    __shared__ __align__(16) unsigned int wlds[P_LDS2 * 1024];   // 48 KB, [p2][j][2]
    __shared__ __align__(16) unsigned short h2u[2][512];         // 2 KB, packed f16 state

    unsigned int wreg[P_REG];
#pragma unroll
    for (int p = 0; p < P_REG; ++p) wreg[p] = wregbuf[p * 512 + j];

    for (int g = j; g < P_LDS2 * 1024; g += 512) wlds[g] = wldsbuf[g];
    h2u[0][j] = 0;   // f16 +0.0
    __syncthreads();

    float* col = xp + (size_t)b * HID + j;
    for (int s = 0; s < S_LEN; ++s) {
        const unsigned int* hq = (const unsigned int*)h2u[s & 1];  // 256 pairs
        float xpv = col[(size_t)s * BH];   // issued here, consumed after the chain

        uint4 sw[P_STR_G];
#pragma unroll
        for (int g = 0; g < P_STR_G; ++g) sw[g] = wstr[(size_t)g * 512 + j];

        float a0 = 0.f, a1 = 0.f, a2 = 0.f, a3 = 0.f;
#pragma unroll
        for (int p = 0; p < P_REG; p += 4) {
            a0 = dot2p(wreg[p + 0], hq[p + 0], a0);
            a1 = dot2p(wreg[p + 1], hq[p + 1], a1);
            a2 = dot2p(wreg[p + 2], hq[p + 2], a2);
            a3 = dot2p(wreg[p + 3], hq[p + 3], a3);
        }
#pragma unroll
        for (int p2 = 0; p2 < P_LDS2; p2 += 2) {   // 12 x ds_read_b64
            uint2 wa = *(const uint2*)&wlds[(p2 + 0) * 1024 + 2 * j];
            uint2 wb = *(const uint2*)&wlds[(p2 + 1) * 1024 + 2 * j];
            int pb = P_REG + 2 * p2;
            a0 = dot2p(wa.x, hq[pb + 0], a0);
            a1 = dot2p(wa.y, hq[pb + 1], a1);
            a2 = dot2p(wb.x, hq[pb + 2], a2);
            a3 = dot2p(wb.y, hq[pb + 3], a3);
        }
#pragma unroll
        for (int g = 0; g < P_STR_G; ++g) {
            int pb = P_REG + P_LDS + 4 * g;
            a0 = dot2p(sw[g].x, hq[pb + 0], a0);
            a1 = dot2p(sw[g].y, hq[pb + 1], a1);
            a2 = dot2p(sw[g].z, hq[pb + 2], a2);
            a3 = dot2p(sw[g].w, hq[pb + 3], a3);
        }

        float v = fast_tanh(((a0 + a1) + (a2 + a3)) + xpv);
        col[(size_t)s * BH] = v;                                   // hidden_seq (fp32)
        h2u[(s + 1) & 1][j] = __builtin_bit_cast(unsigned short, (_Float16)v);
        // Relaxed barrier: wait LDS only; global store/loads stay in flight.
        asm volatile("s_waitcnt lgkmcnt(0)" ::: "memory");
        asm volatile("s_barrier" ::: "memory");
    }
}

// scores: sc_g[b][s] = dot(hbuf[s][b][:], hbuf[S-1][b][:]). Grid (64, 8), 256 thr.
__global__ __launch_bounds__(256) void attn_sc(const float* __restrict__ hbuf,
                                               float* __restrict__ sc_g) {
    const int b     = blockIdx.x;
    const int chunk = blockIdx.y;
    const int tid   = threadIdx.x;
    const int lane  = tid & 63;
    const int wv    = tid >> 6;
    __shared__ float fh[HID];
    fh[tid] = hbuf[(size_t)(S_LEN - 1) * BH + (size_t)b * HID + tid];
    fh[tid + 256] = hbuf[(size_t)(S_LEN - 1) * BH + (size_t)b * HID + tid + 256];
    __syncthreads();
    float4 f0 = *(const float4*)&fh[lane * 8];
    float4 f1 = *(const float4*)&fh[lane * 8 + 4];
    for (int i = 0; i < 32; ++i) {
        int s = chunk * 128 + wv * 32 + i;
        const float* hr = hbuf + (size_t)s * BH + (size_t)b * HID + lane * 8;
        float4 a0 = *(const float4*)hr;
        float4 a1 = *(const float4*)(hr + 4);
        float p = a0.x * f0.x + a0.y * f0.y + a0.z * f0.z + a0.w * f0.w +
                  a1.x * f1.x + a1.y * f1.y + a1.z * f1.z + a1.w * f1.w;
#pragma unroll
        for (int off = 32; off; off >>= 1) p += __shfl_down(p, off, 64);
        if (lane == 0) sc_g[(size_t)b * S_LEN + s] = p;
    }
}

// softmax (redundant per h-chunk) + context. Grid (64, 4), 256 thr, 128 h/WG.
__global__ __launch_bounds__(256) void attn_ctx(const float* __restrict__ hbuf,
                                                const float* __restrict__ sc_g,
                                                float* __restrict__ ctx_g) {
    const int b   = blockIdx.x;
    const int hc  = blockIdx.y * 128;
    const int tid = threadIdx.x;
    const int lane = tid & 63;
    const int wv   = tid >> 6;
    __shared__ float sc[S_LEN];
    __shared__ float red[4];
    __shared__ float part[256];
    for (int i = tid; i < S_LEN; i += 256) sc[i] = sc_g[(size_t)b * S_LEN + i];
    __syncthreads();
    float m = -1e30f;
    for (int i = tid; i < S_LEN; i += 256) m = fmaxf(m, sc[i]);
#pragma unroll
    for (int off = 32; off; off >>= 1) m = fmaxf(m, __shfl_down(m, off, 64));
    if (lane == 0) red[wv] = m;
    __syncthreads();
    m = fmaxf(fmaxf(red[0], red[1]), fmaxf(red[2], red[3]));
    float sum = 0.f;
    for (int i = tid; i < S_LEN; i += 256) {
        float e = __expf(sc[i] - m);
        sc[i] = e;
        sum += e;
    }
#pragma unroll
    for (int off = 32; off; off >>= 1) sum += __shfl_down(sum, off, 64);
    __syncthreads();
    if (lane == 0) red[wv] = sum;
    __syncthreads();
    float inv = 1.f / (red[0] + red[1] + red[2] + red[3]);
    const int h  = hc + (tid & 127);
    const int sh = tid >> 7;
    const float* hp = hbuf + (size_t)sh * 512 * BH + (size_t)b * HID + h;
    float c = 0.f;
#pragma unroll 4
    for (int s2 = 0; s2 < 512; ++s2)
        c += sc[sh * 512 + s2] * hp[(size_t)s2 * BH];
    part[tid] = c;
    __syncthreads();
    if (tid < 128) ctx_g[(size_t)b * HID + hc + tid] = (part[tid] + part[tid + 128]) * inv;
}

// out[b][o] = b_ho[o] + dot(ctx_g[b][:], W_ho[o][:]). Grid 64, 256 thr.
__global__ __launch_bounds__(256) void attn_fin(const float* __restrict__ ctx_g,
                                                const float* __restrict__ W_ho,
                                                const float* __restrict__ b_ho,
                                                float* __restrict__ out) {
    const int b   = blockIdx.x;
    const int tid = threadIdx.x;
    __shared__ float ctx[HID];
    ctx[tid] = ctx_g[(size_t)b * HID + tid];
    ctx[tid + 256] = ctx_g[(size_t)b * HID + tid + 256];
    __syncthreads();
    float o = b_ho[tid];
    const float* wr = W_ho + (size_t)tid * HID;
#pragma unroll 4
    for (int k = 0; k < HID; ++k) o += wr[k] * ctx[k];
    out[(size_t)b * OUT_SZ + tid] = o;
}

extern "C" void kernel_launch(void* const* d_in, const int* in_sizes, int n_in,
                              void* d_out, int out_size, void* d_ws, size_t ws_size,
                              hipStream_t stream) {
    const float* x    = (const float*)d_in[0];
    const float* W_ih = (const float*)d_in[1];
    const float* b_ih = (const float*)d_in[2];
    const float* W_ho = (const float*)d_in[3];
    const float* b_ho = (const float*)d_in[4];
    float* out = (float*)d_out;
    float* ws  = (float*)d_ws;

    float* xp = ws;
    unsigned int* wbase   = (unsigned int*)(ws + XP_FLOATS);
    unsigned int* wstr    = wbase;                         // 28672 words
    unsigned int* wregbuf = wbase + 28672;                 // 90112 words
    unsigned int* wldsbuf = wbase + 28672 + P_REG * 512;   // 12288 words
    uint4*        wpk     = (uint4*)(wbase + 131072);      // 16384 uint4 (256 KB)
    float*        sc_g    = (float*)wbase;                 // overlay, post-rnn
    float*        ctx_g   = (float*)(wbase + 65536);       // overlay, post-rnn

    pack_w<<<dim3(512), dim3(256), 0, stream>>>(W_ih, wstr, wregbuf, wldsbuf);
    pack_wf16<<<dim3(64), dim3(256), 0, stream>>>(W_ih, wpk);
    xproj_mfma<<<dim3(1024, 2), dim3(256), 0, stream>>>(x, wpk, b_ih, xp);
    rnn_f16<<<dim3(64), dim3(512), 0, stream>>>(wregbuf, wldsbuf, (const uint4*)wstr, xp);
    attn_sc<<<dim3(64, 8), dim3(256), 0, stream>>>(xp, sc_g);
    attn_ctx<<<dim3(64, 4), dim3(256), 0, stream>>>(xp, sc_g, ctx_g);
    attn_fin<<<dim3(64), dim3(256), 0, stream>>>(ctx_g, W_ho, b_ho, out);
}